// Round 5
// baseline (122.188 us; speedup 1.0000x reference)
//
#include <hip/hip_runtime.h>

#define IN_F 4096
#define OUT_F 4096
#define KGRP 16
#define N_ROWS (8 * 2048)
#define RPB 8                      // rows per block for srow/out
#define NBLK (N_ROWS / RPB)        // 2048 blocks
#define WPARTS 32                  // wsum partial chunks

typedef float f32x4 __attribute__((ext_vector_type(4)));

// d_ws layout (16B-aligned):
//   [0,      32KB)   : wsum    double[4096]
//   [32KB,   96KB)   : S       float[16384]
//   [96KB,  1120KB)  : partial double[32][4096]

// ---------------------------------------------------------------------------
// Kernel 1a: partial column sums of weight. grid (16, 32) = 512 blocks
// (2 blocks/CU, 8 waves/CU) so HBM latency is hidden; 128 rows per thread,
// unroll 16 -> 16 outstanding loads per thread.
// ---------------------------------------------------------------------------
__global__ __launch_bounds__(256) void wsum_partial_kernel(const float* __restrict__ w,
                                                           double* __restrict__ partial) {
    const int f = blockIdx.x * 256 + threadIdx.x;
    const int r0 = blockIdx.y * (OUT_F / WPARTS);
    const float* p = w + (size_t)r0 * IN_F + f;
    double s = 0.0;
#pragma unroll 16
    for (int o = 0; o < OUT_F / WPARTS; ++o) s += (double)p[(size_t)o * IN_F];
    partial[blockIdx.y * IN_F + f] = s;
}

// Kernel 1b: wsum[f] = sum over 32 partials.
__global__ __launch_bounds__(256) void wsum_reduce_kernel(const double* __restrict__ partial,
                                                          double* __restrict__ wsum) {
    const int f = blockIdx.x * 256 + threadIdx.x;
    double s = 0.0;
#pragma unroll
    for (int p = 0; p < WPARTS; ++p) s += partial[p * IN_F + f];
    wsum[f] = s;
}

// ---------------------------------------------------------------------------
// Kernel 2: pure-read. 2048 blocks x 8 rows; wsum hoisted to registers.
// Folded 4-value 64-lane reduce: 7 shfls (14 ds_bpermute) instead of 24
// shfls (48 bpermute). After xor1+xor2 lane l holds the 4-lane-cluster sum
// of part[l&3]; xor4..32 finish; lanes 0-3 write group (l&3)*4 + wave.
// All accumulation in f64 -> prefix sign-test essentially exact.
// ---------------------------------------------------------------------------
__global__ __launch_bounds__(256) void srow_kernel(const float* __restrict__ x,
                                                   const double* __restrict__ wsum,
                                                   float* __restrict__ S) {
    const int t = threadIdx.x;
    const int lane = t & 63;
    const int wave = t >> 6;
    const int n0 = blockIdx.x * RPB;

    __shared__ double g[RPB][KGRP];

    double wreg[16];
#pragma unroll
    for (int k = 0; k < 4; ++k) {
        const double* wp = &wsum[4 * (k * 256 + t)];
        double2 w01 = *(const double2*)(wp);
        double2 w23 = *(const double2*)(wp + 2);
        wreg[4 * k + 0] = w01.x; wreg[4 * k + 1] = w01.y;
        wreg[4 * k + 2] = w23.x; wreg[4 * k + 3] = w23.y;
    }

    for (int r = 0; r < RPB; ++r) {
        const f32x4* xr = (const f32x4*)(x + (size_t)(n0 + r) * IN_F);
        double part[4];
#pragma unroll
        for (int k = 0; k < 4; ++k) {
            f32x4 v = __builtin_nontemporal_load(&xr[k * 256 + t]);
            part[k] = (double)v.x * wreg[4 * k + 0] + (double)v.y * wreg[4 * k + 1] +
                      (double)v.z * wreg[4 * k + 2] + (double)v.w * wreg[4 * k + 3];
        }
        // --- folded butterfly: 4 values over 64 lanes in 7 shfls ---
        // xor 1: pair-reduce (v0,v1) and (v2,v3) with role swap
        {
            double keep01 = (lane & 1) ? part[1] : part[0];
            double send01 = (lane & 1) ? part[0] : part[1];
            double keep23 = (lane & 1) ? part[3] : part[2];
            double send23 = (lane & 1) ? part[2] : part[3];
            double w01 = keep01 + __shfl_xor(send01, 1, 64);
            double w23 = keep23 + __shfl_xor(send23, 1, 64);
            // xor 2: fold w01/w23 with role swap
            double keep = (lane & 2) ? w23 : w01;
            double send = (lane & 2) ? w01 : w23;
            double rv = keep + __shfl_xor(send, 2, 64);
            // xor 4..32: plain butterfly; lane l accumulates part[l&3] total
#pragma unroll
            for (int off = 4; off <= 32; off <<= 1)
                rv += __shfl_xor(rv, off, 64);
            if (lane < 4) g[r][lane * 4 + wave] = rv;
        }
    }
    __syncthreads();

    if (t < RPB) {
        double cs = 0.0, Sv = 0.0;
        bool found = false;
#pragma unroll
        for (int k = 0; k < KGRP; ++k) {
            cs += g[t][k];
            if (!found && cs >= 0.0) { Sv = cs; found = true; }
        }
        if (!found) Sv = cs;  // no prefix >= 0 -> take total
        S[n0 + t] = (float)Sv;
    }
}

// ---------------------------------------------------------------------------
// Kernel 3: pure-write. 2048 blocks x 8 rows; bias in registers;
// sigmoid via hardware rcp; nontemporal float4 stores.
// ---------------------------------------------------------------------------
__global__ __launch_bounds__(256) void out_kernel(const float* __restrict__ S,
                                                  const float* __restrict__ bias,
                                                  float* __restrict__ out) {
    const int t = threadIdx.x;
    const int n0 = blockIdx.x * RPB;
    const f32x4* b4 = (const f32x4*)bias;

    f32x4 b[4];
#pragma unroll
    for (int k = 0; k < 4; ++k) b[k] = b4[k * 256 + t];

    for (int r = 0; r < RPB; ++r) {
        const float Sv = S[n0 + r];
        f32x4* o4 = (f32x4*)(out + (size_t)(n0 + r) * OUT_F);
#pragma unroll
        for (int k = 0; k < 4; ++k) {
            f32x4 rr;
            rr.x = __builtin_amdgcn_rcpf(1.0f + __expf(-(Sv + b[k].x)));
            rr.y = __builtin_amdgcn_rcpf(1.0f + __expf(-(Sv + b[k].y)));
            rr.z = __builtin_amdgcn_rcpf(1.0f + __expf(-(Sv + b[k].z)));
            rr.w = __builtin_amdgcn_rcpf(1.0f + __expf(-(Sv + b[k].w)));
            __builtin_nontemporal_store(rr, &o4[k * 256 + t]);
        }
    }
}

extern "C" void kernel_launch(void* const* d_in, const int* in_sizes, int n_in,
                              void* d_out, int out_size, void* d_ws, size_t ws_size,
                              hipStream_t stream) {
    const float* x    = (const float*)d_in[0];   // [8,2048,4096] f32
    const float* w    = (const float*)d_in[1];   // [4096,4096]   f32
    const float* bias = (const float*)d_in[2];   // [4096]        f32
    float* out = (float*)d_out;                  // [8,2048,4096] f32

    char* ws = (char*)d_ws;
    double* wsum    = (double*)(ws);                 // 4096 doubles
    float*  S       = (float*)(ws + 32 * 1024);      // 16384 floats
    double* partial = (double*)(ws + 96 * 1024);     // 32*4096 doubles

    dim3 g1(IN_F / 256, WPARTS);
    wsum_partial_kernel<<<g1, 256, 0, stream>>>(w, partial);
    wsum_reduce_kernel<<<IN_F / 256, 256, 0, stream>>>(partial, wsum);
    srow_kernel<<<NBLK, 256, 0, stream>>>(x, wsum, S);
    out_kernel<<<NBLK, 256, 0, stream>>>(S, bias, out);
}